// Round 1
// baseline (1276.499 us; speedup 1.0000x reference)
//
#include <hip/hip_runtime.h>
#include <math.h>

#define Bz 2
#define Tz 2048
#define Cz 1024
#define Hz 16
#define Dz 64
#define Mz (Bz*Tz)   // 4096

// ---------------------------------------------------------------------------
// GEMM: out[m,n] = sum_k A[m,k] * W[n,k] + bias[n]
// A: [Mz,1024] row-major; W: [1024,1024] row-major (torch Linear weight)
// LAYOUT 0: scatter to Q/K/V [B,H,T,D]:  m=b*T+t, n=h*64+d
// LAYOUT 1: plain row-major [Mz,1024]
// 128x128 tile, 256 threads, 8x8 micro-tile, fp32.
// ---------------------------------------------------------------------------
template<int LAYOUT>
__global__ __launch_bounds__(256)
void gemm_bt(const float* __restrict__ A, const float* __restrict__ W,
             const float* __restrict__ bias, float* __restrict__ out)
{
    __shared__ float As[16][132];   // [k][m], stride 132 keeps float4 alignment, banks OK
    __shared__ float Ws[16][132];   // [k][n]
    const int t  = threadIdx.x;
    const int m0 = blockIdx.y * 128;
    const int n0 = blockIdx.x * 128;
    const int tx = t & 15, ty = t >> 4;

    float acc[8][8];
#pragma unroll
    for (int i = 0; i < 8; ++i)
#pragma unroll
        for (int j = 0; j < 8; ++j) acc[i][j] = 0.f;

    for (int k0 = 0; k0 < 1024; k0 += 16) {
#pragma unroll
        for (int p = 0; p < 2; ++p) {
            const int f   = t + p * 256;      // 0..511
            const int row = f >> 2;           // 0..127
            const int c4  = (f & 3) * 4;      // 0,4,8,12
            const float4 av = *(const float4*)&A[(size_t)(m0 + row) * 1024 + k0 + c4];
            As[c4 + 0][row] = av.x; As[c4 + 1][row] = av.y;
            As[c4 + 2][row] = av.z; As[c4 + 3][row] = av.w;
            const float4 wv = *(const float4*)&W[(size_t)(n0 + row) * 1024 + k0 + c4];
            Ws[c4 + 0][row] = wv.x; Ws[c4 + 1][row] = wv.y;
            Ws[c4 + 2][row] = wv.z; Ws[c4 + 3][row] = wv.w;
        }
        __syncthreads();
#pragma unroll
        for (int kk = 0; kk < 16; ++kk) {
            const float4 alo = *(const float4*)&As[kk][ty * 4];
            const float4 ahi = *(const float4*)&As[kk][64 + ty * 4];
            const float4 blo = *(const float4*)&Ws[kk][tx * 4];
            const float4 bhi = *(const float4*)&Ws[kk][64 + tx * 4];
            const float a[8] = {alo.x, alo.y, alo.z, alo.w, ahi.x, ahi.y, ahi.z, ahi.w};
            const float b[8] = {blo.x, blo.y, blo.z, blo.w, bhi.x, bhi.y, bhi.z, bhi.w};
#pragma unroll
            for (int i = 0; i < 8; ++i)
#pragma unroll
                for (int j = 0; j < 8; ++j) acc[i][j] += a[i] * b[j];
        }
        __syncthreads();
    }

    // epilogue
    float bj[8];
#pragma unroll
    for (int j = 0; j < 8; ++j) {
        const int n = n0 + ((j < 4) ? (tx * 4 + j) : (64 + tx * 4 + j - 4));
        bj[j] = bias[n];
    }
#pragma unroll
    for (int i = 0; i < 8; ++i) {
        const int m = m0 + ((i < 4) ? (ty * 4 + i) : (64 + ty * 4 + i - 4));
#pragma unroll
        for (int j = 0; j < 8; ++j) {
            const int n = n0 + ((j < 4) ? (tx * 4 + j) : (64 + tx * 4 + j - 4));
            const float v = acc[i][j] + bj[j];
            if (LAYOUT == 0) {
                const int bb = m >> 11, tt = m & 2047, hh = n >> 6, dd = n & 63;
                out[(((size_t)(bb * Hz + hh)) * Tz + tt) * Dz + dd] = v;
            } else {
                out[(size_t)m * 1024 + n] = v;
            }
        }
    }
}

// ---------------------------------------------------------------------------
// Causal flash attention, fp32. One block = (head-batch bh, 64-row Q tile).
// Q,K,V: [B*H, T, 64]. Output written in [B,T,C] layout.
// ---------------------------------------------------------------------------
__global__ __launch_bounds__(256)
void attn_fwd(const float* __restrict__ Q, const float* __restrict__ K,
              const float* __restrict__ V, float* __restrict__ Obtc)
{
    __shared__ float Qs[64][65];    // padded: column reads during score compute
    __shared__ float KPs[64][65];   // K tile, then reused for P (scores/probs)
    __shared__ float Vs[64][64];    // row-wise float4 reads, no pad needed
    __shared__ float mrow[64], lrow[64], arow[64];

    const int t  = threadIdx.x;
    const int bh = blockIdx.y;           // 0..31
    const int q0 = blockIdx.x * 64;
    const size_t base = (size_t)bh * Tz * Dz;

    // load Q tile (64 x 64)
    for (int f = t; f < 64 * 16; f += 256) {
        const int row = f >> 4, c4 = (f & 15) * 4;
        const float4 v = *(const float4*)&Q[base + (size_t)(q0 + row) * Dz + c4];
        Qs[row][c4 + 0] = v.x; Qs[row][c4 + 1] = v.y;
        Qs[row][c4 + 2] = v.z; Qs[row][c4 + 3] = v.w;
    }
    if (t < 64) { mrow[t] = -INFINITY; lrow[t] = 0.f; }

    const int orow = t >> 2;             // O-accum: this thread's q row
    const int od   = (t & 3) * 16;       // and its 16-wide d slice
    float o[16];
#pragma unroll
    for (int i = 0; i < 16; ++i) o[i] = 0.f;

    const int r0 = (t >> 4) * 4;         // score micro-tile
    const int c0 = (t & 15) * 4;

    for (int s0 = 0; s0 <= q0; s0 += 64) {
        __syncthreads();                 // prev iter done with KPs/Vs (and Q load done)
        for (int f = t; f < 64 * 16; f += 256) {
            const int row = f >> 4, c4 = (f & 15) * 4;
            const float4 kv = *(const float4*)&K[base + (size_t)(s0 + row) * Dz + c4];
            KPs[row][c4 + 0] = kv.x; KPs[row][c4 + 1] = kv.y;
            KPs[row][c4 + 2] = kv.z; KPs[row][c4 + 3] = kv.w;
            const float4 vv = *(const float4*)&V[base + (size_t)(s0 + row) * Dz + c4];
            *(float4*)&Vs[row][c4] = vv;
        }
        __syncthreads();

        // scores: S[r0+i][c0+j] = Q[q0+r0+i] . K[s0+c0+j]
        float sc[4][4];
#pragma unroll
        for (int i = 0; i < 4; ++i)
#pragma unroll
            for (int j = 0; j < 4; ++j) sc[i][j] = 0.f;
        for (int d = 0; d < 64; ++d) {
            const float a0 = Qs[r0 + 0][d], a1 = Qs[r0 + 1][d];
            const float a2 = Qs[r0 + 2][d], a3 = Qs[r0 + 3][d];
            const float b0 = KPs[c0 + 0][d], b1 = KPs[c0 + 1][d];
            const float b2 = KPs[c0 + 2][d], b3 = KPs[c0 + 3][d];
            sc[0][0] += a0 * b0; sc[0][1] += a0 * b1; sc[0][2] += a0 * b2; sc[0][3] += a0 * b3;
            sc[1][0] += a1 * b0; sc[1][1] += a1 * b1; sc[1][2] += a1 * b2; sc[1][3] += a1 * b3;
            sc[2][0] += a2 * b0; sc[2][1] += a2 * b1; sc[2][2] += a2 * b2; sc[2][3] += a2 * b3;
            sc[3][0] += a3 * b0; sc[3][1] += a3 * b1; sc[3][2] += a3 * b2; sc[3][3] += a3 * b3;
        }
        __syncthreads();                 // everyone done reading K tile
#pragma unroll
        for (int i = 0; i < 4; ++i)
#pragma unroll
            for (int j = 0; j < 4; ++j) {
                const int qa = q0 + r0 + i, sa = s0 + c0 + j;
                KPs[r0 + i][c0 + j] = (sa <= qa) ? sc[i][j] * 0.125f : -1e30f;
            }
        __syncthreads();                 // scores visible

        // online softmax: 4 threads per row
        {
            const int row = t >> 2, part = t & 3;
            float mx = -INFINITY;
#pragma unroll
            for (int i = 0; i < 16; ++i) mx = fmaxf(mx, KPs[row][part * 16 + i]);
            mx = fmaxf(mx, __shfl_xor(mx, 1));
            mx = fmaxf(mx, __shfl_xor(mx, 2));
            const float mold = mrow[row];
            const float mnew = fmaxf(mold, mx);
            const float alpha = __expf(mold - mnew);   // mold=-inf -> 0
            float s = 0.f;
#pragma unroll
            for (int i = 0; i < 16; ++i) {
                const float p = __expf(KPs[row][part * 16 + i] - mnew); // -1e30 -> 0
                KPs[row][part * 16 + i] = p;
                s += p;
            }
            s += __shfl_xor(s, 1);
            s += __shfl_xor(s, 2);
            if (part == 0) {
                mrow[row] = mnew;
                lrow[row] = lrow[row] * alpha + s;
                arow[row] = alpha;
            }
        }
        __syncthreads();                 // P + alpha ready

        // O update: o[orow][od..od+15] = o*alpha + sum_c P[orow][c] * V[c][od..]
        {
            const float al = arow[orow];
#pragma unroll
            for (int i = 0; i < 16; ++i) o[i] *= al;
            for (int c = 0; c < 64; ++c) {
                const float p = KPs[orow][c];
                const float4 v0 = *(const float4*)&Vs[c][od + 0];
                const float4 v1 = *(const float4*)&Vs[c][od + 4];
                const float4 v2 = *(const float4*)&Vs[c][od + 8];
                const float4 v3 = *(const float4*)&Vs[c][od + 12];
                o[0]  += p * v0.x; o[1]  += p * v0.y; o[2]  += p * v0.z; o[3]  += p * v0.w;
                o[4]  += p * v1.x; o[5]  += p * v1.y; o[6]  += p * v1.z; o[7]  += p * v1.w;
                o[8]  += p * v2.x; o[9]  += p * v2.y; o[10] += p * v2.z; o[11] += p * v2.w;
                o[12] += p * v3.x; o[13] += p * v3.y; o[14] += p * v3.z; o[15] += p * v3.w;
            }
        }
    }

    // write out in [B,T,C] layout: row (b, q0+orow), cols h*64 + od..
    const float linv = 1.f / lrow[orow];
    const int bb = bh >> 4, hh = bh & 15;
    const size_t ob = ((size_t)bb * Tz + q0 + orow) * Cz + hh * Dz + od;
#pragma unroll
    for (int k4 = 0; k4 < 4; ++k4) {
        const float4 vv = make_float4(o[k4 * 4 + 0] * linv, o[k4 * 4 + 1] * linv,
                                      o[k4 * 4 + 2] * linv, o[k4 * 4 + 3] * linv);
        *(float4*)&Obtc[ob + k4 * 4] = vv;
    }
}

// ---------------------------------------------------------------------------
extern "C" void kernel_launch(void* const* d_in, const int* in_sizes, int n_in,
                              void* d_out, int out_size, void* d_ws, size_t ws_size,
                              hipStream_t stream) {
    const float* x  = (const float*)d_in[0];
    // d_in[1] = att_mask (causal tril) — implied by kernel structure, unused
    const float* wq = (const float*)d_in[2];
    const float* bq = (const float*)d_in[3];
    const float* wk = (const float*)d_in[4];
    const float* bk = (const float*)d_in[5];
    const float* wv = (const float*)d_in[6];
    const float* bv = (const float*)d_in[7];
    const float* wp = (const float*)d_in[8];
    const float* bp = (const float*)d_in[9];
    float* out = (float*)d_out;

    float* ws = (float*)d_ws;
    const size_t mat = (size_t)Mz * Cz;       // 4096*1024 floats = 16 MB
    float* Qb = ws;
    float* Kb = ws + mat;
    float* Vb = ws + 2 * mat;
    float* AO = ws + 3 * mat;                 // attention output in [B,T,C]

    const dim3 gg(Cz / 128, Mz / 128);        // (8, 32)
    const dim3 blk(256);
    hipLaunchKernelGGL((gemm_bt<0>), gg, blk, 0, stream, x, wq, bq, Qb);
    hipLaunchKernelGGL((gemm_bt<0>), gg, blk, 0, stream, x, wk, bk, Kb);
    hipLaunchKernelGGL((gemm_bt<0>), gg, blk, 0, stream, x, wv, bv, Vb);

    const dim3 ga(Tz / 64, Bz * Hz);          // (32, 32)
    hipLaunchKernelGGL(attn_fwd, ga, blk, 0, stream, Qb, Kb, Vb, AO);

    hipLaunchKernelGGL((gemm_bt<1>), gg, blk, 0, stream, AO, wp, bp, out);
}

// Round 2
// 316.063 us; speedup vs baseline: 4.0388x; 4.0388x over previous
//
#include <hip/hip_runtime.h>
#include <math.h>

#define Bz 2
#define Tz 2048
#define Cz 1024
#define Hz 16
#define Dz 64
#define Mz (Bz*Tz)   // 4096

typedef short bf16x8 __attribute__((ext_vector_type(8)));
typedef float f32x4  __attribute__((ext_vector_type(4)));

__device__ __forceinline__ unsigned short f2bf(float f) {
    union { float f; unsigned u; } v; v.f = f;
    unsigned r = v.u + 0x7fffu + ((v.u >> 16) & 1u);   // RNE
    return (unsigned short)(r >> 16);
}

// async global->LDS, 16B per lane; LDS dest = wave-uniform base + lane*16
#define GLD16(gp, lp) __builtin_amdgcn_global_load_lds( \
    (const __attribute__((address_space(1))) unsigned int*)(gp), \
    (__attribute__((address_space(3))) unsigned int*)(lp), 16, 0, 0)

// ---------------------------------------------------------------------------
// cast fp32 -> bf16: x (4M elems), wq,wk,wv (into wqkvb), wp (into wpb)
// 8M total elems, 4 per thread.
// ---------------------------------------------------------------------------
__global__ __launch_bounds__(256)
void cast_all(const float* __restrict__ x,  const float* __restrict__ wq,
              const float* __restrict__ wk, const float* __restrict__ wv,
              const float* __restrict__ wp,
              unsigned short* __restrict__ xb, unsigned short* __restrict__ wqkvb,
              unsigned short* __restrict__ wpb)
{
    const size_t M1 = 1u << 20;
    size_t i = ((size_t)blockIdx.x * 256 + threadIdx.x) * 4;
    const float* s; unsigned short* d; size_t o;
    int reg = (int)(i >> 20);
    if      (reg < 4)  { s = x;  d = xb;           o = i;          }
    else if (reg == 4) { s = wq; d = wqkvb;        o = i - 4 * M1; }
    else if (reg == 5) { s = wk; d = wqkvb + M1;   o = i - 5 * M1; }
    else if (reg == 6) { s = wv; d = wqkvb + 2*M1; o = i - 6 * M1; }
    else               { s = wp; d = wpb;          o = i - 7 * M1; }
    float4 v = *(const float4*)&s[o];
    ushort4 u;
    u.x = f2bf(v.x); u.y = f2bf(v.y); u.z = f2bf(v.z); u.w = f2bf(v.w);
    *(ushort4*)&d[o] = u;
}

// ---------------------------------------------------------------------------
// bf16 MFMA GEMM: out[m,n] = sum_k A[m,k]*W[n,k] + bias[n]
// A: [Mz, 1024] bf16 row-major; W: [N, 1024] bf16 row-major.
// Tile: (AI*32) x 128, 256 threads (4 waves, 2x2), 16x16x32 MFMA, BK=32.
// EPI 0: N=3072, scatter QKV -> bf16 [B,H,T,D] x3.
// EPI 1: N=1024, fp32 out [Mz,1024].
// ---------------------------------------------------------------------------
template<int AI, int EPI>
__global__ __launch_bounds__(256)
void mfma_gemm(const unsigned short* __restrict__ A, const unsigned short* __restrict__ W,
               const float* __restrict__ bias, void* out0, void* out1, void* out2)
{
    __shared__ unsigned short As[AI * 32][32];
    __shared__ unsigned short Bs[128][32];
    const int t = threadIdx.x, w = t >> 6, l = t & 63;
    const int m0 = blockIdx.y * (AI * 32);
    const int n0 = blockIdx.x * 128;
    const int wr = w >> 1, wc = w & 1;
    const int g = l >> 4, ln = l & 15;

    f32x4 acc[AI][4];
#pragma unroll
    for (int i = 0; i < AI; ++i)
#pragma unroll
        for (int j = 0; j < 4; ++j) acc[i][j] = (f32x4){0.f, 0.f, 0.f, 0.f};

    for (int k0 = 0; k0 < 1024; k0 += 32) {
        __syncthreads();
#pragma unroll
        for (int p = 0; p < AI / 2; ++p) {
            const int rb = (w * (AI / 2) + p) * 16;
            GLD16(A + (size_t)(m0 + rb + (l >> 2)) * 1024 + k0 + (l & 3) * 8,
                  (unsigned short*)As + rb * 32);
        }
#pragma unroll
        for (int p = 0; p < 2; ++p) {
            const int rb = (w * 2 + p) * 16;
            GLD16(W + (size_t)(n0 + rb + (l >> 2)) * 1024 + k0 + (l & 3) * 8,
                  (unsigned short*)Bs + rb * 32);
        }
        __syncthreads();
        bf16x8 af[AI], bf[4];
#pragma unroll
        for (int i = 0; i < AI; ++i)
            af[i] = *(const bf16x8*)&As[wr * (AI * 16) + i * 16 + ln][g * 8];
#pragma unroll
        for (int j = 0; j < 4; ++j)
            bf[j] = *(const bf16x8*)&Bs[wc * 64 + j * 16 + ln][g * 8];
#pragma unroll
        for (int i = 0; i < AI; ++i)
#pragma unroll
            for (int j = 0; j < 4; ++j)
                acc[i][j] = __builtin_amdgcn_mfma_f32_16x16x32_bf16(af[i], bf[j], acc[i][j], 0, 0, 0);
    }

    // epilogue: C/D layout col=ln, row=g*4+reg
    if (EPI == 0) {
        unsigned short* qd = (unsigned short*)out0;
        unsigned short* kd = (unsigned short*)out1;
        unsigned short* vd = (unsigned short*)out2;
#pragma unroll
        for (int i = 0; i < AI; ++i)
#pragma unroll
            for (int j = 0; j < 4; ++j) {
                const int gn = n0 + wc * 64 + j * 16 + ln;
                const float bj = bias[gn];
                const int sel = gn >> 10, rem = gn & 1023, h = rem >> 6, dd = rem & 63;
                unsigned short* dst = (sel == 0) ? qd : ((sel == 1) ? kd : vd);
#pragma unroll
                for (int r = 0; r < 4; ++r) {
                    const int gm = m0 + wr * (AI * 16) + i * 16 + g * 4 + r;
                    const int b = gm >> 11, tt = gm & 2047;
                    dst[(size_t)((b * Hz + h) * Tz + tt) * Dz + dd] = f2bf(acc[i][j][r] + bj);
                }
            }
    } else {
        float* od = (float*)out0;
#pragma unroll
        for (int i = 0; i < AI; ++i)
#pragma unroll
            for (int j = 0; j < 4; ++j) {
                const int gn = n0 + wc * 64 + j * 16 + ln;
                const float bj = bias[gn];
#pragma unroll
                for (int r = 0; r < 4; ++r) {
                    const int gm = m0 + wr * (AI * 16) + i * 16 + g * 4 + r;
                    od[(size_t)gm * 1024 + gn] = acc[i][j][r] + bj;
                }
            }
    }
}

// ---------------------------------------------------------------------------
// MFMA flash attention, causal. bf16 Q,K,V in [B*H, T, 64].
// Block: 256 thr (4 waves), 64 Q-rows (16 per wave), K-tiles of 64.
// Output: bf16 AO in [B,T,C].
// ---------------------------------------------------------------------------
__global__ __launch_bounds__(256)
void attn_mfma(const unsigned short* __restrict__ Q, const unsigned short* __restrict__ K,
               const unsigned short* __restrict__ V, unsigned short* __restrict__ AO)
{
    __shared__ unsigned short Ks[64][64];     // [key][d]   8 KB
    __shared__ unsigned short Vt[64][64];     // [d][key]   8 KB
    __shared__ unsigned short Ps[4][16][64];  // per-wave P 8 KB

    const int t = threadIdx.x, w = t >> 6, l = t & 63;
    const int g = l >> 4, ln = l & 15;
    const int bh = blockIdx.y;
    const int q0 = blockIdx.x * 64;
    const size_t hb = (size_t)bh * Tz * Dz;

    // Q fragments direct from global (A-layout: m=ln, k=g*8+j, 2 k-steps)
    bf16x8 qf[2];
#pragma unroll
    for (int ss = 0; ss < 2; ++ss)
        qf[ss] = *(const bf16x8*)&Q[hb + (size_t)(q0 + w * 16 + ln) * Dz + ss * 32 + g * 8];

    f32x4 o[4];
#pragma unroll
    for (int j = 0; j < 4; ++j) o[j] = (f32x4){0.f, 0.f, 0.f, 0.f};
    float m[4]    = {-__builtin_inff(), -__builtin_inff(), -__builtin_inff(), -__builtin_inff()};
    float lsum[4] = {0.f, 0.f, 0.f, 0.f};

    for (int kt = 0; kt <= q0; kt += 64) {
        __syncthreads();   // previous iteration's consumers of Ks/Vt done
        // stage K tile (contiguous 8KB in global) via async global->LDS
#pragma unroll
        for (int p = 0; p < 2; ++p) {
            const int rb = (w * 2 + p) * 8;   // 8 key-rows per instr (row = 128B = 8 lanes)
            GLD16(K + hb + (size_t)(kt + rb + (l >> 3)) * Dz + (l & 7) * 8,
                  (unsigned short*)Ks + rb * 64);
        }
        // stage V transposed: thread handles keys {2kp,2kp+1}, d-slice dc*8..+7
        {
            const int kp = t & 31, dc = t >> 5;
            bf16x8 v0 = *(const bf16x8*)&V[hb + (size_t)(kt + 2 * kp)     * Dz + dc * 8];
            bf16x8 v1 = *(const bf16x8*)&V[hb + (size_t)(kt + 2 * kp + 1) * Dz + dc * 8];
#pragma unroll
            for (int jj = 0; jj < 8; ++jj) {
                ushort2 u;
                u.x = (unsigned short)v0[jj];
                u.y = (unsigned short)v1[jj];
                *(ushort2*)&Vt[dc * 8 + jj][2 * kp] = u;
            }
        }
        __syncthreads();   // staging visible

        // S = Q K^T  (C layout: col(key)=ln, row(q)=g*4+r)
        f32x4 s[4];
#pragma unroll
        for (int j = 0; j < 4; ++j) s[j] = (f32x4){0.f, 0.f, 0.f, 0.f};
#pragma unroll
        for (int j = 0; j < 4; ++j)
#pragma unroll
            for (int ss = 0; ss < 2; ++ss) {
                bf16x8 kf = *(const bf16x8*)&Ks[j * 16 + ln][ss * 32 + g * 8];
                s[j] = __builtin_amdgcn_mfma_f32_16x16x32_bf16(qf[ss], kf, s[j], 0, 0, 0);
            }

        // mask + scale in place
#pragma unroll
        for (int j = 0; j < 4; ++j) {
            const int key = kt + j * 16 + ln;
#pragma unroll
            for (int r = 0; r < 4; ++r) {
                const int q = q0 + w * 16 + g * 4 + r;
                s[j][r] = (key <= q) ? s[j][r] * 0.125f : -__builtin_inff();
            }
        }

        // online softmax per row (16-lane group shfl reductions)
#pragma unroll
        for (int r = 0; r < 4; ++r) {
            float mx = fmaxf(fmaxf(s[0][r], s[1][r]), fmaxf(s[2][r], s[3][r]));
            mx = fmaxf(mx, __shfl_xor(mx, 1));
            mx = fmaxf(mx, __shfl_xor(mx, 2));
            mx = fmaxf(mx, __shfl_xor(mx, 4));
            mx = fmaxf(mx, __shfl_xor(mx, 8));
            const float mn = fmaxf(m[r], mx);
            const float al = __expf(m[r] - mn);   // -inf first iter -> 0
            float rs = 0.f;
#pragma unroll
            for (int j = 0; j < 4; ++j) {
                const float p = __expf(s[j][r] - mn);
                rs += p;
                Ps[w][g * 4 + r][j * 16 + ln] = f2bf(p);
            }
            rs += __shfl_xor(rs, 1);
            rs += __shfl_xor(rs, 2);
            rs += __shfl_xor(rs, 4);
            rs += __shfl_xor(rs, 8);
            lsum[r] = lsum[r] * al + rs;
            m[r] = mn;
#pragma unroll
            for (int j2 = 0; j2 < 4; ++j2) o[j2][r] *= al;
        }

        // O += P V   (A from Ps, B from Vt; same-wave LDS ops are in-order)
#pragma unroll
        for (int ss = 0; ss < 2; ++ss) {
            bf16x8 pf = *(const bf16x8*)&Ps[w][ln][ss * 32 + g * 8];
#pragma unroll
            for (int j2 = 0; j2 < 4; ++j2) {
                bf16x8 vf = *(const bf16x8*)&Vt[j2 * 16 + ln][ss * 32 + g * 8];
                o[j2] = __builtin_amdgcn_mfma_f32_16x16x32_bf16(pf, vf, o[j2], 0, 0, 0);
            }
        }
    }

    // epilogue -> AO bf16 [B,T,C]
    const int b = bh >> 4, h = bh & 15;
#pragma unroll
    for (int r = 0; r < 4; ++r) {
        const float linv = 1.f / lsum[r];
        const int row = b * Tz + q0 + w * 16 + g * 4 + r;
#pragma unroll
        for (int j2 = 0; j2 < 4; ++j2)
            AO[(size_t)row * Cz + h * Dz + j2 * 16 + ln] = f2bf(o[j2][r] * linv);
    }
}

// ---------------------------------------------------------------------------
extern "C" void kernel_launch(void* const* d_in, const int* in_sizes, int n_in,
                              void* d_out, int out_size, void* d_ws, size_t ws_size,
                              hipStream_t stream) {
    const float* x  = (const float*)d_in[0];
    // d_in[1] = att_mask (causal tril) — implied by kernel structure, unused
    const float* wq = (const float*)d_in[2];
    const float* bq = (const float*)d_in[3];
    const float* wk = (const float*)d_in[4];
    const float* bk = (const float*)d_in[5];
    const float* wv = (const float*)d_in[6];
    const float* bv = (const float*)d_in[7];
    const float* wp = (const float*)d_in[8];
    const float* bp = (const float*)d_in[9];
    float* out = (float*)d_out;

    char* wsb = (char*)d_ws;
    unsigned short* xb    = (unsigned short*)(wsb);                       // 8 MB
    unsigned short* wqkvb = (unsigned short*)(wsb + (8u  << 20));         // 6 MB
    unsigned short* wpb   = (unsigned short*)(wsb + (14u << 20));         // 2 MB
    float*          bqkv  = (float*)         (wsb + (16u << 20));         // 12 KB
    unsigned short* Qb    = (unsigned short*)(wsb + (17u << 20));         // 8 MB
    unsigned short* Kb    = (unsigned short*)(wsb + (25u << 20));         // 8 MB
    unsigned short* Vb    = (unsigned short*)(wsb + (33u << 20));         // 8 MB
    unsigned short* AOb   = (unsigned short*)(wsb + (41u << 20));         // 8 MB

    hipLaunchKernelGGL(cast_all, dim3(8192), dim3(256), 0, stream,
                       x, wq, wk, wv, wp, xb, wqkvb, wpb);
    hipMemcpyAsync(bqkv,        bq, Cz * sizeof(float), hipMemcpyDeviceToDevice, stream);
    hipMemcpyAsync(bqkv + Cz,   bk, Cz * sizeof(float), hipMemcpyDeviceToDevice, stream);
    hipMemcpyAsync(bqkv + 2*Cz, bv, Cz * sizeof(float), hipMemcpyDeviceToDevice, stream);

    // fused QKV: [4096 x 3072 x 1024]
    hipLaunchKernelGGL((mfma_gemm<4, 0>), dim3(24, 32), dim3(256), 0, stream,
                       xb, wqkvb, bqkv, Qb, Kb, Vb);

    // attention
    hipLaunchKernelGGL(attn_mfma, dim3(Tz / 64, Bz * Hz), dim3(256), 0, stream,
                       Qb, Kb, Vb, AOb);

    // output projection: [4096 x 1024 x 1024], 64-row tiles for 2 blocks/CU
    hipLaunchKernelGGL((mfma_gemm<2, 1>), dim3(8, 64), dim3(256), 0, stream,
                       AOb, wpb, bp, out, nullptr, nullptr);
}

// Round 3
// 248.592 us; speedup vs baseline: 5.1349x; 1.2714x over previous
//
#include <hip/hip_runtime.h>
#include <math.h>

#define Bz 2
#define Tz 2048
#define Cz 1024
#define Hz 16
#define Dz 64
#define Mz (Bz*Tz)   // 4096

typedef short bf16x8 __attribute__((ext_vector_type(8)));
typedef short bf16x4 __attribute__((ext_vector_type(4)));
typedef float f32x4  __attribute__((ext_vector_type(4)));

__device__ __forceinline__ unsigned short f2bf(float f) {
    union { float f; unsigned u; } v; v.f = f;
    unsigned r = v.u + 0x7fffu + ((v.u >> 16) & 1u);   // RNE
    return (unsigned short)(r >> 16);
}

// async global->LDS, 16B per lane; LDS dest = wave-uniform base + lane*16
#define GLD16(gp, lp) __builtin_amdgcn_global_load_lds( \
    (const __attribute__((address_space(1))) unsigned int*)(gp), \
    (__attribute__((address_space(3))) unsigned int*)(lp), 16, 0, 0)

// ---------------------------------------------------------------------------
// cast fp32 -> bf16: x (4M elems), wq,wk,wv (into wqkvb), wp (into wpb)
// ---------------------------------------------------------------------------
__global__ __launch_bounds__(256)
void cast_all(const float* __restrict__ x,  const float* __restrict__ wq,
              const float* __restrict__ wk, const float* __restrict__ wv,
              const float* __restrict__ wp,
              unsigned short* __restrict__ xb, unsigned short* __restrict__ wqkvb,
              unsigned short* __restrict__ wpb)
{
    const size_t M1 = 1u << 20;
    size_t i = ((size_t)blockIdx.x * 256 + threadIdx.x) * 4;
    const float* s; unsigned short* d; size_t o;
    int reg = (int)(i >> 20);
    if      (reg < 4)  { s = x;  d = xb;           o = i;          }
    else if (reg == 4) { s = wq; d = wqkvb;        o = i - 4 * M1; }
    else if (reg == 5) { s = wk; d = wqkvb + M1;   o = i - 5 * M1; }
    else if (reg == 6) { s = wv; d = wqkvb + 2*M1; o = i - 6 * M1; }
    else               { s = wp; d = wpb;          o = i - 7 * M1; }
    float4 v = *(const float4*)&s[o];
    ushort4 u;
    u.x = f2bf(v.x); u.y = f2bf(v.y); u.z = f2bf(v.z); u.w = f2bf(v.w);
    *(ushort4*)&d[o] = u;
}

// ---------------------------------------------------------------------------
// bf16 MFMA GEMM: out[m,n] = sum_k A[m,k]*W[n,k] + bias[n]
// EPI 0 (N=3072): Q -> [B,H,T,D] * 0.125 ; K -> [B,H,T,D] ; V -> Vt [B,H,D,T]
// EPI 1 (N=1024): fp32 out [Mz,1024]
// ---------------------------------------------------------------------------
template<int AI, int EPI>
__global__ __launch_bounds__(256)
void mfma_gemm(const unsigned short* __restrict__ A, const unsigned short* __restrict__ W,
               const float* __restrict__ b0, const float* __restrict__ b1,
               const float* __restrict__ b2,
               void* out0, void* out1, void* out2)
{
    __shared__ unsigned short As[AI * 32][32];
    __shared__ unsigned short Bs[128][32];
    const int t = threadIdx.x, w = t >> 6, l = t & 63;
    const int m0 = blockIdx.y * (AI * 32);
    const int n0 = blockIdx.x * 128;
    const int wr = w >> 1, wc = w & 1;
    const int g = l >> 4, ln = l & 15;

    f32x4 acc[AI][4];
#pragma unroll
    for (int i = 0; i < AI; ++i)
#pragma unroll
        for (int j = 0; j < 4; ++j) acc[i][j] = (f32x4){0.f, 0.f, 0.f, 0.f};

    for (int k0 = 0; k0 < 1024; k0 += 32) {
        __syncthreads();
#pragma unroll
        for (int p = 0; p < AI / 2; ++p) {
            const int rb = (w * (AI / 2) + p) * 16;
            GLD16(A + (size_t)(m0 + rb + (l >> 2)) * 1024 + k0 + (l & 3) * 8,
                  (unsigned short*)As + rb * 32);
        }
#pragma unroll
        for (int p = 0; p < 2; ++p) {
            const int rb = (w * 2 + p) * 16;
            GLD16(W + (size_t)(n0 + rb + (l >> 2)) * 1024 + k0 + (l & 3) * 8,
                  (unsigned short*)Bs + rb * 32);
        }
        __syncthreads();
        bf16x8 af[AI], bf[4];
#pragma unroll
        for (int i = 0; i < AI; ++i)
            af[i] = *(const bf16x8*)&As[wr * (AI * 16) + i * 16 + ln][g * 8];
#pragma unroll
        for (int j = 0; j < 4; ++j)
            bf[j] = *(const bf16x8*)&Bs[wc * 64 + j * 16 + ln][g * 8];
#pragma unroll
        for (int i = 0; i < AI; ++i)
#pragma unroll
            for (int j = 0; j < 4; ++j)
                acc[i][j] = __builtin_amdgcn_mfma_f32_16x16x32_bf16(af[i], bf[j], acc[i][j], 0, 0, 0);
    }

    if (EPI == 0) {
        unsigned short* qd = (unsigned short*)out0;
        unsigned short* kd = (unsigned short*)out1;
        unsigned short* vd = (unsigned short*)out2;
#pragma unroll
        for (int i = 0; i < AI; ++i)
#pragma unroll
            for (int j = 0; j < 4; ++j) {
                const int gn = n0 + wc * 64 + j * 16 + ln;
                const int sel = gn >> 10, rem = gn & 1023, h = rem >> 6, dd = rem & 63;
                const float bj = (sel == 0) ? b0[rem] : ((sel == 1) ? b1[rem] : b2[rem]);
#pragma unroll
                for (int r = 0; r < 4; ++r) {
                    const int gm = m0 + wr * (AI * 16) + i * 16 + g * 4 + r;
                    const int b = gm >> 11, tt = gm & 2047;
                    if (sel == 0)
                        qd[(size_t)((b * Hz + h) * Tz + tt) * Dz + dd] = f2bf((acc[i][j][r] + bj) * 0.125f);
                    else if (sel == 1)
                        kd[(size_t)((b * Hz + h) * Tz + tt) * Dz + dd] = f2bf(acc[i][j][r] + bj);
                    else
                        vd[((size_t)(b * Hz + h) * Dz + dd) * Tz + tt] = f2bf(acc[i][j][r] + bj);
                }
            }
    } else {
        float* od = (float*)out0;
#pragma unroll
        for (int i = 0; i < AI; ++i)
#pragma unroll
            for (int j = 0; j < 4; ++j) {
                const int gn = n0 + wc * 64 + j * 16 + ln;
                const float bj = b0[gn];
#pragma unroll
                for (int r = 0; r < 4; ++r) {
                    const int gm = m0 + wr * (AI * 16) + i * 16 + g * 4 + r;
                    od[(size_t)gm * 1024 + gn] = acc[i][j][r] + bj;
                }
            }
    }
}

// ---------------------------------------------------------------------------
// Barrier-free wave-flash attention. 1 wave = 32 Q rows, sweeps causal K.
// Q,K: bf16 [B*H, T, 64] (Q pre-scaled by 0.125). Vt: bf16 [B*H, 64, T].
// Grid (bh=32, cg=16); wave w -> chunk (15-cg)*4 + w; heavy chunks first.
// Only LDS use: per-wave P round-trip (C-layout -> A-layout). No barriers.
// ---------------------------------------------------------------------------
__global__ __launch_bounds__(256, 2)
void attn_wave(const unsigned short* __restrict__ Q, const unsigned short* __restrict__ K,
               const unsigned short* __restrict__ Vt, unsigned short* __restrict__ AO)
{
    __shared__ unsigned short Ps[4][32][68];   // stride 68: conflict-free b16 writes, 8B-aligned rows

    const int t = threadIdx.x, w = t >> 6, l = t & 63;
    const int g = l >> 4, ln = l & 15;
    const int bh = blockIdx.x;                       // head pinned to XCD bh%8
    const int chunk = (15 - blockIdx.y) * 4 + w;     // 0..63, heavy first
    const int q0 = chunk * 32;
    const size_t hb = (size_t)bh * Tz * Dz;          // elem offset for K and Vt alike

    // Q fragments (A-layout: m=ln, k=g*8+j), rows q0+i2*16+ln
    bf16x8 qf[2][2];
#pragma unroll
    for (int i2 = 0; i2 < 2; ++i2)
#pragma unroll
        for (int ss = 0; ss < 2; ++ss)
            qf[i2][ss] = *(const bf16x8*)&Q[hb + (size_t)(q0 + i2 * 16 + ln) * Dz + ss * 32 + g * 8];

    f32x4 o[2][4];
    float m[2][4], lr[2][4];
#pragma unroll
    for (int i2 = 0; i2 < 2; ++i2)
#pragma unroll
        for (int r = 0; r < 4; ++r) { m[i2][r] = -__builtin_inff(); lr[i2][r] = 0.f; }
#pragma unroll
    for (int i2 = 0; i2 < 2; ++i2)
#pragma unroll
        for (int j = 0; j < 4; ++j) o[i2][j] = (f32x4){0.f, 0.f, 0.f, 0.f};

    const short ONE = 0x3F80;  // bf16 1.0
    const bf16x8 onef = {ONE, ONE, ONE, ONE, ONE, ONE, ONE, ONE};

    const int ktLast = (q0 >> 6) << 6;   // the single (partially) masked tile

    for (int kt = 0; kt <= q0; kt += 64) {
        // K fragments (B-layout: n=key=j*16+ln, k=ss*32+g*8)
        bf16x8 kf[4][2];
#pragma unroll
        for (int j = 0; j < 4; ++j)
#pragma unroll
            for (int ss = 0; ss < 2; ++ss)
                kf[j][ss] = *(const bf16x8*)&K[hb + (size_t)(kt + j * 16 + ln) * Dz + ss * 32 + g * 8];
        // V^T fragments (B-layout: n=d=j2*16+ln, k=key) — issue early, used after softmax
        bf16x8 vf[4][2];
#pragma unroll
        for (int j2 = 0; j2 < 4; ++j2)
#pragma unroll
            for (int ss = 0; ss < 2; ++ss)
                vf[j2][ss] = *(const bf16x8*)&Vt[hb + (size_t)(j2 * 16 + ln) * Tz + kt + ss * 32 + g * 8];

        // S = Q K^T  (1/sqrt(D) folded into Q)
        f32x4 s[2][4];
#pragma unroll
        for (int i2 = 0; i2 < 2; ++i2)
#pragma unroll
            for (int j = 0; j < 4; ++j) s[i2][j] = (f32x4){0.f, 0.f, 0.f, 0.f};
#pragma unroll
        for (int i2 = 0; i2 < 2; ++i2)
#pragma unroll
            for (int j = 0; j < 4; ++j)
#pragma unroll
                for (int ss = 0; ss < 2; ++ss)
                    s[i2][j] = __builtin_amdgcn_mfma_f32_16x16x32_bf16(qf[i2][ss], kf[j][ss], s[i2][j], 0, 0, 0);

        if (kt == ktLast) {   // diagonal tile: causal mask
#pragma unroll
            for (int i2 = 0; i2 < 2; ++i2)
#pragma unroll
                for (int j = 0; j < 4; ++j) {
                    const int key = kt + j * 16 + ln;
#pragma unroll
                    for (int r = 0; r < 4; ++r) {
                        const int q = q0 + i2 * 16 + g * 4 + r;
                        if (key > q) s[i2][j][r] = -__builtin_inff();
                    }
                }
        }

        // online softmax: max via 16-lane shfl; sum via ones-MFMA below
        float al[2][4];
#pragma unroll
        for (int i2 = 0; i2 < 2; ++i2)
#pragma unroll
            for (int r = 0; r < 4; ++r) {
                float mx = fmaxf(fmaxf(s[i2][0][r], s[i2][1][r]), fmaxf(s[i2][2][r], s[i2][3][r]));
                mx = fmaxf(mx, __shfl_xor(mx, 1));
                mx = fmaxf(mx, __shfl_xor(mx, 2));
                mx = fmaxf(mx, __shfl_xor(mx, 4));
                mx = fmaxf(mx, __shfl_xor(mx, 8));
                const float mn = fmaxf(m[i2][r], mx);
                al[i2][r] = __expf(m[i2][r] - mn);
                m[i2][r] = mn;
                const int row = i2 * 16 + g * 4 + r;
#pragma unroll
                for (int j = 0; j < 4; ++j) {
                    const float p = __expf(s[i2][j][r] - mn);
                    Ps[w][row][j * 16 + ln] = (unsigned short)(__float_as_uint(p) >> 16); // trunc bf16
                }
            }
        // rescale O
#pragma unroll
        for (int i2 = 0; i2 < 2; ++i2)
#pragma unroll
            for (int j2 = 0; j2 < 4; ++j2)
#pragma unroll
                for (int r = 0; r < 4; ++r) o[i2][j2][r] *= al[i2][r];

        // P (A-layout, b64 reads) + PV + row-sum via ones-MFMA
        f32x4 lt[2] = {(f32x4){0.f,0.f,0.f,0.f}, (f32x4){0.f,0.f,0.f,0.f}};
#pragma unroll
        for (int i2 = 0; i2 < 2; ++i2)
#pragma unroll
            for (int ss = 0; ss < 2; ++ss) {
                const bf16x4 plo = *(const bf16x4*)&Ps[w][i2 * 16 + ln][ss * 32 + g * 8];
                const bf16x4 phi = *(const bf16x4*)&Ps[w][i2 * 16 + ln][ss * 32 + g * 8 + 4];
                bf16x8 pf;
#pragma unroll
                for (int q4 = 0; q4 < 4; ++q4) { pf[q4] = plo[q4]; pf[4 + q4] = phi[q4]; }
                lt[i2] = __builtin_amdgcn_mfma_f32_16x16x32_bf16(pf, onef, lt[i2], 0, 0, 0);
#pragma unroll
                for (int j2 = 0; j2 < 4; ++j2)
                    o[i2][j2] = __builtin_amdgcn_mfma_f32_16x16x32_bf16(pf, vf[j2][ss], o[i2][j2], 0, 0, 0);
            }
#pragma unroll
        for (int i2 = 0; i2 < 2; ++i2)
#pragma unroll
            for (int r = 0; r < 4; ++r) lr[i2][r] = lr[i2][r] * al[i2][r] + lt[i2][r];
    }

    // epilogue -> AO bf16 [B,T,C]
    const int b = bh >> 4, h = bh & 15;
#pragma unroll
    for (int i2 = 0; i2 < 2; ++i2)
#pragma unroll
        for (int r = 0; r < 4; ++r) {
            const float linv = 1.f / lr[i2][r];
            const int row = b * Tz + q0 + i2 * 16 + g * 4 + r;
#pragma unroll
            for (int j2 = 0; j2 < 4; ++j2)
                AO[(size_t)row * Cz + h * Dz + j2 * 16 + ln] = f2bf(o[i2][j2][r] * linv);
        }
}

// ---------------------------------------------------------------------------
extern "C" void kernel_launch(void* const* d_in, const int* in_sizes, int n_in,
                              void* d_out, int out_size, void* d_ws, size_t ws_size,
                              hipStream_t stream) {
    const float* x  = (const float*)d_in[0];
    // d_in[1] = att_mask (causal tril) — implied by kernel structure, unused
    const float* wq = (const float*)d_in[2];
    const float* bq = (const float*)d_in[3];
    const float* wk = (const float*)d_in[4];
    const float* bk = (const float*)d_in[5];
    const float* wv = (const float*)d_in[6];
    const float* bv = (const float*)d_in[7];
    const float* wp = (const float*)d_in[8];
    const float* bp = (const float*)d_in[9];
    float* out = (float*)d_out;

    char* wsb = (char*)d_ws;
    unsigned short* xb    = (unsigned short*)(wsb);                       // 8 MB
    unsigned short* wqkvb = (unsigned short*)(wsb + (8u  << 20));         // 6 MB
    unsigned short* wpb   = (unsigned short*)(wsb + (14u << 20));         // 2 MB
    unsigned short* Qb    = (unsigned short*)(wsb + (17u << 20));         // 8 MB
    unsigned short* Kb    = (unsigned short*)(wsb + (25u << 20));         // 8 MB
    unsigned short* Vtb   = (unsigned short*)(wsb + (33u << 20));         // 8 MB (transposed)
    unsigned short* AOb   = (unsigned short*)(wsb + (41u << 20));         // 8 MB

    hipLaunchKernelGGL(cast_all, dim3(8192), dim3(256), 0, stream,
                       x, wq, wk, wv, wp, xb, wqkvb, wpb);

    // fused QKV: [4096 x 3072 x 1024]
    hipLaunchKernelGGL((mfma_gemm<4, 0>), dim3(24, 32), dim3(256), 0, stream,
                       xb, wqkvb, bq, bk, bv, Qb, Kb, Vtb);

    // attention: head-per-XCD swizzle, heavy chunk groups first, barrier-free
    hipLaunchKernelGGL(attn_wave, dim3(32, 16), dim3(256), 0, stream,
                       Qb, Kb, Vtb, AOb);

    // output projection: [4096 x 1024 x 1024]
    hipLaunchKernelGGL((mfma_gemm<2, 1>), dim3(8, 64), dim3(256), 0, stream,
                       AOb, wpb, bp, bp, bp, out, nullptr, nullptr);
}